// Round 7
// baseline (456.548 us; speedup 1.0000x reference)
//
#include <hip/hip_runtime.h>
#include <math.h>

#define NN 11
#define RR 8192               // B*L positions
#define DD 1024
#define EPSV 1e-5f
#define PREP_TPB 256

// ---- ws layout (floats) ----
// wvec : [22][1024]      @ 0        (q*gamma; attn 0..10, mlp 0..10)
// scal : [22][2]         @ 22528    (sum(q*g), sum(q*b)); padded to 64
// dots : [24][11][8192]  @ 22592    (j: 0..10 dA, 11..21 dM, 22 sum, 23 ssq)
// pack : [8192][264]     @ 2185280  (per-pos: w1[121], lg2[121], Ahd[11], mu_h[11])
#define OFF_SCAL 22528
#define OFF_DOTS 22592
#define OFF_PACK 2185280

__device__ __forceinline__ float wave_reduce(float v) {
#pragma unroll
  for (int o = 32; o > 0; o >>= 1) v += __shfl_xor(v, o, 64);
  return v;
}

__device__ __forceinline__ float dot4(const float4 a, const float4 b) {
  return a.x*b.x + a.y*b.y + a.z*b.z + a.w*b.w;
}

__global__ __launch_bounds__(PREP_TPB) void prep_kernel(
    const float* __restrict__ aq, const float* __restrict__ ag, const float* __restrict__ ab,
    const float* __restrict__ mq, const float* __restrict__ mg, const float* __restrict__ mb,
    float* __restrict__ wvec, float* __restrict__ scal)
{
  const int j = blockIdx.x;              // 0..21
  const float *q, *g, *bt;
  if (j < NN) { q = aq + (size_t)j*DD;      g = ag + (size_t)j*DD;      bt = ab + (size_t)j*DD; }
  else        { q = mq + (size_t)(j-NN)*DD; g = mg + (size_t)(j-NN)*DD; bt = mb + (size_t)(j-NN)*DD; }
  const int t = threadIdx.x;
  float sqg = 0.f, sqb = 0.f;
  for (int d = t; d < DD; d += PREP_TPB) {
    float qq = q[d];
    float w  = qq * g[d];
    wvec[(size_t)j*DD + d] = w;
    sqg += w;
    sqb += qq * bt[d];
  }
  sqg = wave_reduce(sqg);
  sqb = wave_reduce(sqb);
  __shared__ float red[2][PREP_TPB/64];
  const int lane = t & 63, wid = t >> 6;
  if (lane == 0) { red[0][wid] = sqg; red[1][wid] = sqb; }
  __syncthreads();
  if (t == 0) {
    float a = 0.f, b2 = 0.f;
    for (int w = 0; w < PREP_TPB/64; ++w) { a += red[0][w]; b2 += red[1][w]; }
    scal[2*j]   = a;
    scal[2*j+1] = b2;
  }
}

// K1: block = (n, 64 positions), K=1024 in 8 LDS rounds of 128. 8 waves:
// waves 0-3 = attn dots (j 0..10), waves 4-7 = mlp dots + sum/ssq. Each wave
// keeps a wave-uniform 32-float k-window (weight reads stay scalar s_loads);
// halved chains/wave + 8 waves/SIMD of TLP cover the s_load latency.
__global__ __launch_bounds__(512, 8) void dots_kernel(
    const float* __restrict__ streams, const float* __restrict__ wvec,
    float* __restrict__ dots)
{
  __shared__ float tile[8192];           // 32 KB: [64 pos][128 k] XOR-swizzled; reused for partials

  const int n   = blockIdx.x / 128;      // stream index 0..10
  const int p0  = (blockIdx.x % 128) * 64;
  const int t   = threadIdx.x;
  const int pos = t & 63;
  const int w   = __builtin_amdgcn_readfirstlane(t >> 6);   // wave id 0..7
  const int kwv = (w & 3) << 5;          // k-window offset 0/32/64/96
  const int jt  = w >> 2;                // 0: attn j-rows 0..10, 1: mlp rows 11..21 (+stats)
  const int sw  = (pos & 7) << 2;        // read-side XOR swizzle (float units)

  float acc[11];
#pragma unroll
  for (int j = 0; j < 11; ++j) acc[j] = 0.f;
  float sum = 0.f, ssq = 0.f;

  for (int kc = 0; kc < 8; ++kc) {
    // ---- stage 64 pos x 128 k (2048 float4s, 4 per thread), coalesced ----
#pragma unroll
    for (int i = 0; i < 4; ++i) {
      const int f4  = i*512 + t;         // float4 index, 0..2047
      const int row = f4 >> 5;           // 0..63 (32 float4 per row)
      const int col = f4 & 31;
      float4 v = *(const float4*)(streams + ((size_t)(n*RR + p0 + row))*DD + kc*128 + col*4);
      const int fidx = (row*128 + col*4) ^ ((row & 7) << 2);
      *(float4*)&tile[fidx] = v;
    }
    __syncthreads();

    // ---- pull this thread's 32-float window into registers ----
    float4 xv[8];
#pragma unroll
    for (int e = 0; e < 8; ++e) {
      const int f = (pos*128 + kwv + e*4) ^ sw;
      xv[e] = *(const float4*)&tile[f];
    }
    __syncthreads();                     // tile free for next round's writes

    // ---- stats only on the mlp wave-team ----
    if (jt == 1) {
#pragma unroll
      for (int e = 0; e < 8; ++e) {
        sum += xv[e].x + xv[e].y + xv[e].z + xv[e].w;
        ssq  = fmaf(xv[e].x, xv[e].x, ssq);
        ssq  = fmaf(xv[e].y, xv[e].y, ssq);
        ssq  = fmaf(xv[e].z, xv[e].z, ssq);
        ssq  = fmaf(xv[e].w, xv[e].w, ssq);
      }
    }

    // ---- 11 dot partials; weight address wave-uniform -> scalar loads ----
    const float* wbase = wvec + (size_t)(jt*NN)*DD + kc*128 + kwv;
#pragma unroll
    for (int j = 0; j < 11; ++j) {
      const float* wr = wbase + (size_t)j*DD;
      float a = acc[j];
#pragma unroll
      for (int e = 0; e < 8; ++e) {
        a = fmaf(wr[e*4+0], xv[e].x, a);
        a = fmaf(wr[e*4+1], xv[e].y, a);
        a = fmaf(wr[e*4+2], xv[e].z, a);
        a = fmaf(wr[e*4+3], xv[e].w, a);
      }
      acc[j] = a;
    }
  }

  // ---- partials in reused tile: [8 waves][64 pos][13 slots] = 6656 floats ----
  {
    float* part = tile + (size_t)w*832 + pos*13;
#pragma unroll
    for (int j = 0; j < 11; ++j) part[j] = acc[j];
    if (jt == 1) { part[11] = sum; part[12] = ssq; }
  }
  __syncthreads();

  // ---- final reduce over the 4 k-segment waves, write dots (3 per thread) ----
#pragma unroll
  for (int q = 0; q < 3; ++q) {
    const int o    = t*3 + q;            // 0..1535
    const int pos2 = o / 24;
    const int j2   = o % 24;
    const int base = (j2 < 11) ? 0 : 4;
    const int slot = (j2 < 11) ? j2 : (j2 < 22 ? j2 - 11 : (j2 == 22 ? 11 : 12));
    float s = tile[(base+0)*832 + pos2*13 + slot]
            + tile[(base+1)*832 + pos2*13 + slot]
            + tile[(base+2)*832 + pos2*13 + slot]
            + tile[(base+3)*832 + pos2*13 + slot];
    dots[((size_t)j2*NN + n)*RR + p0 + pos2] = s;
  }
}

// K2: one thread per position. Softmax pass-1 weights, pass-2 logit pieces.
__global__ __launch_bounds__(256) void coef_kernel(
    const float* __restrict__ dots, const float* __restrict__ scal,
    float* __restrict__ pack)
{
  const int p = blockIdx.x*256 + threadIdx.x;      // 8192 threads exactly
  float mu[NN], rs[NN];
#pragma unroll
  for (int n = 0; n < NN; ++n) {
    float s  = dots[((size_t)22*NN + n)*RR + p];
    float q2 = dots[((size_t)23*NN + n)*RR + p];
    mu[n] = s * (1.f/DD);
    rs[n] = rsqrtf(q2*(1.f/DD) - mu[n]*mu[n] + EPSV);
  }
  float* pk = pack + (size_t)p*264;
  for (int i = 0; i < NN; ++i) {                   // uniform runtime i
    const float qgA = scal[2*i],        qbA = scal[2*i+1];
    const float qgM = scal[2*(NN+i)],   qbM = scal[2*(NN+i)+1];
    float w1[NN];
    float mx = -3.0e38f;
#pragma unroll
    for (int n = 0; n < NN; ++n) if (n <= i) {
      float dA = dots[((size_t)i*NN + n)*RR + p];
      float lg = (dA - mu[n]*qgA)*rs[n] + qbA;
      w1[n] = lg;
      mx = fmaxf(mx, lg);
    }
    float S = 0.f;
#pragma unroll
    for (int n = 0; n < NN; ++n) if (n <= i) { float e = __expf(w1[n]-mx); w1[n] = e; S += e; }
    float inv = 1.f/S;
    float muh = 0.f, hd = 0.f;
#pragma unroll
    for (int n = 0; n < NN; ++n) if (n <= i) {
      w1[n] *= inv;
      float dM = dots[((size_t)(NN+i)*NN + n)*RR + p];
      muh += w1[n]*mu[n];
      hd  += w1[n]*dM;
      pk[i*NN + n] = w1[n];
      if (n < i) pk[121 + i*NN + n] = (dM - mu[n]*qgM)*rs[n] + qbM;
    }
    pk[242 + i] = hd - muh*qgM;
    pk[253 + i] = muh;
  }
}

// K3: one block per position: h sumsq (11 wave reduces), finish logits,
// build C row, combine to out. Streams read once, out written once.
__global__ __launch_bounds__(256) void combine_kernel(
    const float* __restrict__ streams,
    const float* __restrict__ pack,
    const float* __restrict__ scal,
    float* __restrict__ out)
{
  __shared__ float P[264];
  __shared__ float red[4][12];
  __shared__ float C[121];

  const int p = blockIdx.x;
  const int t = threadIdx.x;
  const int lane = t & 63, w = t >> 6;

  for (int s = t; s < 264; s += 256) P[s] = pack[(size_t)p*264 + s];

  float4 x[NN];
#pragma unroll
  for (int n = 0; n < NN; ++n)
    x[n] = *(const float4*)(streams + ((size_t)n*RR + p)*DD + 4*t);
  __syncthreads();

  // h sumsq per i
  float hss[NN];
#pragma unroll
  for (int i = 0; i < NN; ++i) {
    float4 h = make_float4(0.f,0.f,0.f,0.f);
#pragma unroll
    for (int n = 0; n < NN; ++n) if (n <= i) {
      float wv = P[i*NN + n];
      h.x = fmaf(wv, x[n].x, h.x);
      h.y = fmaf(wv, x[n].y, h.y);
      h.z = fmaf(wv, x[n].z, h.z);
      h.w = fmaf(wv, x[n].w, h.w);
    }
    hss[i] = dot4(h, h);
  }
#pragma unroll
  for (int i = 0; i < NN; ++i) hss[i] = wave_reduce(hss[i]);
  if (lane == 0) {
#pragma unroll
    for (int i = 0; i < NN; ++i) red[w][i] = hss[i];
  }
  __syncthreads();

  if (t < NN) {
    const int i = t;
    float hs   = red[0][i] + red[1][i] + red[2][i] + red[3][i];
    float mu_h = P[253 + i];
    float Ahd  = P[242 + i];
    float varh = hs*(1.f/DD) - mu_h*mu_h;
    float rsh  = rsqrtf(varh + EPSV);
    float qbM  = scal[2*(NN+i)+1];
    float lgh  = Ahd*rsh + qbM;

    float mx2 = lgh;
#pragma unroll
    for (int n = 0; n < NN; ++n) if (n < i) mx2 = fmaxf(mx2, P[121 + i*NN + n]);
    float w2[NN];
    float eh = __expf(lgh - mx2);
    float S2 = eh;
#pragma unroll
    for (int n = 0; n < NN; ++n) if (n < i) {
      float e = __expf(P[121 + i*NN + n] - mx2);
      w2[n] = e;
      S2 += e;
    }
    float inv2 = 1.f/S2;
    float ehw  = eh*inv2;
#pragma unroll
    for (int n = 0; n < NN; ++n) {
      float cc = 0.f;
      if (n < i)  cc = w2[n]*inv2;
      if (n <= i) cc += ehw*P[i*NN + n];
      C[i*NN + n] = cc;
    }
  }
  __syncthreads();

#pragma unroll
  for (int i = 0; i < NN; ++i) {
    float4 o = make_float4(0.f,0.f,0.f,0.f);
#pragma unroll
    for (int n = 0; n < NN; ++n) {
      float cc = C[i*NN + n];
      o.x = fmaf(cc, x[n].x, o.x);
      o.y = fmaf(cc, x[n].y, o.y);
      o.z = fmaf(cc, x[n].z, o.z);
      o.w = fmaf(cc, x[n].w, o.w);
    }
    *(float4*)(out + ((size_t)i*RR + p)*DD + 4*t) = o;
  }
}

extern "C" void kernel_launch(void* const* d_in, const int* in_sizes, int n_in,
                              void* d_out, int out_size, void* d_ws, size_t ws_size,
                              hipStream_t stream) {
  const float* streams = (const float*)d_in[0];
  const float* aq = (const float*)d_in[1];
  const float* ag = (const float*)d_in[2];
  const float* ab = (const float*)d_in[3];
  const float* mq = (const float*)d_in[4];
  const float* mg = (const float*)d_in[5];
  const float* mb = (const float*)d_in[6];
  float* outp = (float*)d_out;

  float* wsf  = (float*)d_ws;
  float* wvec = wsf;
  float* scal = wsf + OFF_SCAL;
  float* dots = wsf + OFF_DOTS;
  float* pack = wsf + OFF_PACK;

  prep_kernel<<<dim3(2*NN), dim3(PREP_TPB), 0, stream>>>(aq, ag, ab, mq, mg, mb, wvec, scal);
  dots_kernel<<<dim3(NN*128), dim3(512), 0, stream>>>(streams, wvec, dots);
  coef_kernel<<<dim3(RR/256), dim3(256), 0, stream>>>(dots, scal, pack);
  combine_kernel<<<dim3(RR), dim3(256), 0, stream>>>(streams, pack, scal, outp);
}

// Round 8
// 291.478 us; speedup vs baseline: 1.5663x; 1.5663x over previous
//
#include <hip/hip_runtime.h>
#include <math.h>

#define NN 11
#define RR 8192               // B*L positions
#define DD 1024
#define EPSV 1e-5f
#define PREP_TPB 256

// ---- ws layout (floats) ----
// wvec : [22][1024]      @ 0        (q*gamma; attn 0..10, mlp 0..10)
// scal : [22][2]         @ 22528    (sum(q*g), sum(q*b)); padded to 64
// dots : [24][11][8192]  @ 22592    (j: 0..10 dA, 11..21 dM, 22 sum, 23 ssq)
// pack : [8192][264]     @ 2185280  (per-pos: w1[121], lg2[121], Ahd[11], mu_h[11])
#define OFF_SCAL 22528
#define OFF_DOTS 22592
#define OFF_PACK 2185280

__device__ __forceinline__ float wave_reduce(float v) {
#pragma unroll
  for (int o = 32; o > 0; o >>= 1) v += __shfl_xor(v, o, 64);
  return v;
}

__device__ __forceinline__ float dot4(const float4 a, const float4 b) {
  return a.x*b.x + a.y*b.y + a.z*b.z + a.w*b.w;
}

__global__ __launch_bounds__(PREP_TPB) void prep_kernel(
    const float* __restrict__ aq, const float* __restrict__ ag, const float* __restrict__ ab,
    const float* __restrict__ mq, const float* __restrict__ mg, const float* __restrict__ mb,
    float* __restrict__ wvec, float* __restrict__ scal)
{
  const int j = blockIdx.x;              // 0..21
  const float *q, *g, *bt;
  if (j < NN) { q = aq + (size_t)j*DD;      g = ag + (size_t)j*DD;      bt = ab + (size_t)j*DD; }
  else        { q = mq + (size_t)(j-NN)*DD; g = mg + (size_t)(j-NN)*DD; bt = mb + (size_t)(j-NN)*DD; }
  const int t = threadIdx.x;
  float sqg = 0.f, sqb = 0.f;
  for (int d = t; d < DD; d += PREP_TPB) {
    float qq = q[d];
    float w  = qq * g[d];
    wvec[(size_t)j*DD + d] = w;
    sqg += w;
    sqb += qq * bt[d];
  }
  sqg = wave_reduce(sqg);
  sqb = wave_reduce(sqb);
  __shared__ float red[2][PREP_TPB/64];
  const int lane = t & 63, wid = t >> 6;
  if (lane == 0) { red[0][wid] = sqg; red[1][wid] = sqb; }
  __syncthreads();
  if (t == 0) {
    float a = 0.f, b2 = 0.f;
    for (int w = 0; w < PREP_TPB/64; ++w) { a += red[0][w]; b2 += red[1][w]; }
    scal[2*j]   = a;
    scal[2*j+1] = b2;
  }
}

// K1: block = (n, 64 positions), K=1024 in 8 LDS rounds of 128. 8 waves:
// waves 0-3 = attn dots (j 0..10), waves 4-7 = mlp dots + sum/ssq. Each wave
// keeps a wave-uniform 32-float k-window (weight reads stay scalar s_loads).
// launch_bounds(512,4): cap 128 VGPR -- actual need ~60, no spill; HW still
// co-resides 8 waves/SIMD since actual allocation <= 64.
__global__ __launch_bounds__(512, 4) void dots_kernel(
    const float* __restrict__ streams, const float* __restrict__ wvec,
    float* __restrict__ dots)
{
  __shared__ float tile[8192];           // 32 KB: [64 pos][128 k] XOR-swizzled; reused for partials

  const int n   = blockIdx.x / 128;      // stream index 0..10
  const int p0  = (blockIdx.x % 128) * 64;
  const int t   = threadIdx.x;
  const int pos = t & 63;
  const int w   = __builtin_amdgcn_readfirstlane(t >> 6);   // wave id 0..7
  const int kwv = (w & 3) << 5;          // k-window offset 0/32/64/96
  const int jt  = w >> 2;                // 0: attn j-rows 0..10, 1: mlp rows 11..21 (+stats)
  const int sw  = (pos & 7) << 2;        // read-side XOR swizzle (float units)

  float acc[11];
#pragma unroll
  for (int j = 0; j < 11; ++j) acc[j] = 0.f;
  float sum = 0.f, ssq = 0.f;

  for (int kc = 0; kc < 8; ++kc) {
    // ---- stage 64 pos x 128 k (2048 float4s, 4 per thread), coalesced ----
#pragma unroll
    for (int i = 0; i < 4; ++i) {
      const int f4  = i*512 + t;         // float4 index, 0..2047
      const int row = f4 >> 5;           // 0..63 (32 float4 per row)
      const int col = f4 & 31;
      float4 v = *(const float4*)(streams + ((size_t)(n*RR + p0 + row))*DD + kc*128 + col*4);
      const int fidx = (row*128 + col*4) ^ ((row & 7) << 2);
      *(float4*)&tile[fidx] = v;
    }
    __syncthreads();

    // ---- pull this thread's 32-float window into registers ----
    float4 xv[8];
#pragma unroll
    for (int e = 0; e < 8; ++e) {
      const int f = (pos*128 + kwv + e*4) ^ sw;
      xv[e] = *(const float4*)&tile[f];
    }
    __syncthreads();                     // tile free for next round's writes

    // ---- stats only on the mlp wave-team ----
    if (jt == 1) {
#pragma unroll
      for (int e = 0; e < 8; ++e) {
        sum += xv[e].x + xv[e].y + xv[e].z + xv[e].w;
        ssq  = fmaf(xv[e].x, xv[e].x, ssq);
        ssq  = fmaf(xv[e].y, xv[e].y, ssq);
        ssq  = fmaf(xv[e].z, xv[e].z, ssq);
        ssq  = fmaf(xv[e].w, xv[e].w, ssq);
      }
    }

    // ---- 11 dot partials; weight address wave-uniform -> scalar loads ----
    const float* wbase = wvec + (size_t)(jt*NN)*DD + kc*128 + kwv;
#pragma unroll
    for (int j = 0; j < 11; ++j) {
      const float* wr = wbase + (size_t)j*DD;
      float a = acc[j];
#pragma unroll
      for (int e = 0; e < 8; ++e) {
        a = fmaf(wr[e*4+0], xv[e].x, a);
        a = fmaf(wr[e*4+1], xv[e].y, a);
        a = fmaf(wr[e*4+2], xv[e].z, a);
        a = fmaf(wr[e*4+3], xv[e].w, a);
      }
      acc[j] = a;
    }
  }

  // ---- partials in reused tile: [8 waves][64 pos][13 slots] = 6656 floats ----
  {
    float* part = tile + (size_t)w*832 + pos*13;
#pragma unroll
    for (int j = 0; j < 11; ++j) part[j] = acc[j];
    if (jt == 1) { part[11] = sum; part[12] = ssq; }
  }
  __syncthreads();

  // ---- final reduce over the 4 k-segment waves, write dots (3 per thread) ----
#pragma unroll
  for (int q = 0; q < 3; ++q) {
    const int o    = t*3 + q;            // 0..1535
    const int pos2 = o / 24;
    const int j2   = o % 24;
    const int base = (j2 < 11) ? 0 : 4;
    const int slot = (j2 < 11) ? j2 : (j2 < 22 ? j2 - 11 : (j2 == 22 ? 11 : 12));
    float s = tile[(base+0)*832 + pos2*13 + slot]
            + tile[(base+1)*832 + pos2*13 + slot]
            + tile[(base+2)*832 + pos2*13 + slot]
            + tile[(base+3)*832 + pos2*13 + slot];
    dots[((size_t)j2*NN + n)*RR + p0 + pos2] = s;
  }
}

// K2: one thread per position. Softmax pass-1 weights, pass-2 logit pieces.
__global__ __launch_bounds__(256) void coef_kernel(
    const float* __restrict__ dots, const float* __restrict__ scal,
    float* __restrict__ pack)
{
  const int p = blockIdx.x*256 + threadIdx.x;      // 8192 threads exactly
  float mu[NN], rs[NN];
#pragma unroll
  for (int n = 0; n < NN; ++n) {
    float s  = dots[((size_t)22*NN + n)*RR + p];
    float q2 = dots[((size_t)23*NN + n)*RR + p];
    mu[n] = s * (1.f/DD);
    rs[n] = rsqrtf(q2*(1.f/DD) - mu[n]*mu[n] + EPSV);
  }
  float* pk = pack + (size_t)p*264;
  for (int i = 0; i < NN; ++i) {                   // uniform runtime i
    const float qgA = scal[2*i],        qbA = scal[2*i+1];
    const float qgM = scal[2*(NN+i)],   qbM = scal[2*(NN+i)+1];
    float w1[NN];
    float mx = -3.0e38f;
#pragma unroll
    for (int n = 0; n < NN; ++n) if (n <= i) {
      float dA = dots[((size_t)i*NN + n)*RR + p];
      float lg = (dA - mu[n]*qgA)*rs[n] + qbA;
      w1[n] = lg;
      mx = fmaxf(mx, lg);
    }
    float S = 0.f;
#pragma unroll
    for (int n = 0; n < NN; ++n) if (n <= i) { float e = __expf(w1[n]-mx); w1[n] = e; S += e; }
    float inv = 1.f/S;
    float muh = 0.f, hd = 0.f;
#pragma unroll
    for (int n = 0; n < NN; ++n) if (n <= i) {
      w1[n] *= inv;
      float dM = dots[((size_t)(NN+i)*NN + n)*RR + p];
      muh += w1[n]*mu[n];
      hd  += w1[n]*dM;
      pk[i*NN + n] = w1[n];
      if (n < i) pk[121 + i*NN + n] = (dM - mu[n]*qgM)*rs[n] + qbM;
    }
    pk[242 + i] = hd - muh*qgM;
    pk[253 + i] = muh;
  }
}

// K3: one block per position: h sumsq (11 wave reduces), finish logits,
// build C row, combine to out. Streams read once, out written once.
__global__ __launch_bounds__(256) void combine_kernel(
    const float* __restrict__ streams,
    const float* __restrict__ pack,
    const float* __restrict__ scal,
    float* __restrict__ out)
{
  __shared__ float P[264];
  __shared__ float red[4][12];
  __shared__ float C[121];

  const int p = blockIdx.x;
  const int t = threadIdx.x;
  const int lane = t & 63, w = t >> 6;

  for (int s = t; s < 264; s += 256) P[s] = pack[(size_t)p*264 + s];

  float4 x[NN];
#pragma unroll
  for (int n = 0; n < NN; ++n)
    x[n] = *(const float4*)(streams + ((size_t)n*RR + p)*DD + 4*t);
  __syncthreads();

  // h sumsq per i
  float hss[NN];
#pragma unroll
  for (int i = 0; i < NN; ++i) {
    float4 h = make_float4(0.f,0.f,0.f,0.f);
#pragma unroll
    for (int n = 0; n < NN; ++n) if (n <= i) {
      float wv = P[i*NN + n];
      h.x = fmaf(wv, x[n].x, h.x);
      h.y = fmaf(wv, x[n].y, h.y);
      h.z = fmaf(wv, x[n].z, h.z);
      h.w = fmaf(wv, x[n].w, h.w);
    }
    hss[i] = dot4(h, h);
  }
#pragma unroll
  for (int i = 0; i < NN; ++i) hss[i] = wave_reduce(hss[i]);
  if (lane == 0) {
#pragma unroll
    for (int i = 0; i < NN; ++i) red[w][i] = hss[i];
  }
  __syncthreads();

  if (t < NN) {
    const int i = t;
    float hs   = red[0][i] + red[1][i] + red[2][i] + red[3][i];
    float mu_h = P[253 + i];
    float Ahd  = P[242 + i];
    float varh = hs*(1.f/DD) - mu_h*mu_h;
    float rsh  = rsqrtf(varh + EPSV);
    float qbM  = scal[2*(NN+i)+1];
    float lgh  = Ahd*rsh + qbM;

    float mx2 = lgh;
#pragma unroll
    for (int n = 0; n < NN; ++n) if (n < i) mx2 = fmaxf(mx2, P[121 + i*NN + n]);
    float w2[NN];
    float eh = __expf(lgh - mx2);
    float S2 = eh;
#pragma unroll
    for (int n = 0; n < NN; ++n) if (n < i) {
      float e = __expf(P[121 + i*NN + n] - mx2);
      w2[n] = e;
      S2 += e;
    }
    float inv2 = 1.f/S2;
    float ehw  = eh*inv2;
#pragma unroll
    for (int n = 0; n < NN; ++n) {
      float cc = 0.f;
      if (n < i)  cc = w2[n]*inv2;
      if (n <= i) cc += ehw*P[i*NN + n];
      C[i*NN + n] = cc;
    }
  }
  __syncthreads();

#pragma unroll
  for (int i = 0; i < NN; ++i) {
    float4 o = make_float4(0.f,0.f,0.f,0.f);
#pragma unroll
    for (int n = 0; n < NN; ++n) {
      float cc = C[i*NN + n];
      o.x = fmaf(cc, x[n].x, o.x);
      o.y = fmaf(cc, x[n].y, o.y);
      o.z = fmaf(cc, x[n].z, o.z);
      o.w = fmaf(cc, x[n].w, o.w);
    }
    *(float4*)(out + ((size_t)i*RR + p)*DD + 4*t) = o;
  }
}

extern "C" void kernel_launch(void* const* d_in, const int* in_sizes, int n_in,
                              void* d_out, int out_size, void* d_ws, size_t ws_size,
                              hipStream_t stream) {
  const float* streams = (const float*)d_in[0];
  const float* aq = (const float*)d_in[1];
  const float* ag = (const float*)d_in[2];
  const float* ab = (const float*)d_in[3];
  const float* mq = (const float*)d_in[4];
  const float* mg = (const float*)d_in[5];
  const float* mb = (const float*)d_in[6];
  float* outp = (float*)d_out;

  float* wsf  = (float*)d_ws;
  float* wvec = wsf;
  float* scal = wsf + OFF_SCAL;
  float* dots = wsf + OFF_DOTS;
  float* pack = wsf + OFF_PACK;

  prep_kernel<<<dim3(2*NN), dim3(PREP_TPB), 0, stream>>>(aq, ag, ab, mq, mg, mb, wvec, scal);
  dots_kernel<<<dim3(NN*128), dim3(512), 0, stream>>>(streams, wvec, dots);
  coef_kernel<<<dim3(RR/256), dim3(256), 0, stream>>>(dots, scal, pack);
  combine_kernel<<<dim3(RR), dim3(256), 0, stream>>>(streams, pack, scal, outp);
}